// Round 7
// baseline (848.417 us; speedup 1.0000x reference)
//
#include <hip/hip_runtime.h>

// Conv2d 3x3 SAME, stride 1: x (16,64,256,256) f32, w (128,64,3,3), bias (128) -> out (16,128,256,256)
//
// V8: fp16 MFMA implicit-GEMM, swapped-operand epilogue.
//  - x -> padded NHWC f16 workspace x_p[n][258][258][64] (1-px zero border).
//  - conv: 256 blocks (4 strips x 4 bands x 16 n) x 512 thr; 8 waves x 16 couts each.
//    Per-wave A = 18 half8 = 72 VGPR, register-persistent.
//  - V8 CHANGE: mfma(bt, af, acc) — operand swap (A/B lane layouts are identical for
//    16x16x32_f16). D becomes row=pixel, col=cout: lane ln&15=cout, (l>>4)*4+r = 4
//    CONSECUTIVE pixels -> each acc frag stores as one NT dwordx4 directly.
//    Kills V7's LDS-scratch epilogue (64 ds_write + 16 ds_read per lane per iter,
//    ~4.5k cyc/CU/iter on the binding LDS pipe) and its serial tail chain.
//  - Raw s_barrier + counted s_waitcnt vmcnt(16): staging drains, the 16 NT stores/iter
//    stay in flight across the barrier (retire under next iter's compute).
//  - s_setprio(1) around the MFMA/ds_read compute loop (T5; waves are phase-diverse).
//  - Staging/swizzle bit-identical to verified V4..V7: unit swizzle ((s^(c&7))<<4),
//    F = c*128 + (((4h+g)^(c&7))<<4) -> 0 bank conflicts.

typedef _Float16 half8_t __attribute__((ext_vector_type(8)));
typedef float floatx4 __attribute__((ext_vector_type(4)));

#define HH 256
#define WW 256
#define CIN 64
#define COUT 128
#define NB 16

#define XP_RSTRIDE   16512            // halves per padded row (258*64)
#define XP_NSTRIDE   4260096          // halves per n (258*16512)
#define XP_RSTRIDE_B 33024            // bytes per padded row
#define ROW_LDS      8448             // bytes per LDS tile row (66 cols * 128 B)
#define TILE_BYTES   50688            // 6 * ROW_LDS

__device__ inline void gload_lds16(const void* g, void* l) {
    __builtin_amdgcn_global_load_lds(
        (const __attribute__((address_space(1))) unsigned int*)g,
        (__attribute__((address_space(3))) unsigned int*)l, 16, 0, 0);
}

// ---------- pass 1a: weights OIHW f32 -> w_t[9][8][128][8] f16 ----------
__global__ void Conv2d_wprep_kernel(const float* __restrict__ w, _Float16* __restrict__ w_t) {
    int idx = blockIdx.x * 256 + threadIdx.x;
    if (idx >= 9 * 8 * 128 * 8) return;
    const int j = idx & 7, cout = (idx >> 3) & 127, s = (idx >> 10) & 7, t = idx >> 13;
    w_t[idx] = (_Float16)w[(cout * 64 + s * 8 + j) * 9 + t];
}

// ---------- pass 1b-zero: zero the 1-px border of x_p ----------
__global__ void Conv2d_xpad_zero_kernel(_Float16* __restrict__ xp) {
    const int idx = blockIdx.x * 256 + threadIdx.x;   // 16B units, 8224 per n
    const int n = blockIdx.y;
    if (idx >= 8224) return;
    size_t off;  // in halves
    if (idx < 2064)      off = (size_t)idx * 8;                                    // row 0
    else if (idx < 4128) off = (size_t)257 * XP_RSTRIDE + (size_t)(idx - 2064) * 8; // row 257
    else if (idx < 6176) { const int t = idx - 4128;                               // col 0
        off = (size_t)(1 + (t >> 3)) * XP_RSTRIDE + (size_t)(t & 7) * 8; }
    else { const int t = idx - 6176;                                               // col 257
        off = (size_t)(1 + (t >> 3)) * XP_RSTRIDE + 257 * 64 + (size_t)(t & 7) * 8; }
    int4 z = {0, 0, 0, 0};
    *(int4*)(xp + (size_t)n * XP_NSTRIDE + off) = z;
}

// ---------- pass 1b: x NCHW f32 -> padded NHWC f16 (LDS-free transpose) ----------
__global__ __launch_bounds__(256) void Conv2d_xprep_kernel(const float* __restrict__ x,
                                                           _Float16* __restrict__ xp) {
    const int tid = threadIdx.x;
    const int u = tid & 7, colq = tid >> 3;
    const int n = blockIdx.z, h = blockIdx.y;
    const int col0 = blockIdx.x * 128 + colq * 4;

    float4 in[8];
#pragma unroll
    for (int j = 0; j < 8; ++j)
        in[j] = *(const float4*)(x + ((size_t)((n * 64 + u * 8 + j) * 256 + h) * 256) + col0);

    _Float16* dst = xp + (size_t)n * XP_NSTRIDE + (size_t)(h + 1) * XP_RSTRIDE +
                    (size_t)(col0 + 1) * 64 + u * 8;
#pragma unroll
    for (int i = 0; i < 4; ++i) {
        half8_t hv;
#pragma unroll
        for (int j = 0; j < 8; ++j) hv[j] = (_Float16)((const float*)&in[j])[i];
        *(half8_t*)(dst + (size_t)i * 64) = hv;
    }
}

// ---------- conv: persistent strips, register weights, direct float4 epilogue ----------
__global__ __launch_bounds__(512, 2) void Conv2dManual_77695958385099_kernel(
    const _Float16* __restrict__ xp, const _Float16* __restrict__ w_t,
    const float* __restrict__ bias, float* __restrict__ out) {
    __shared__ __align__(16) unsigned char xs[2 * TILE_BYTES];  // 101376 B
    const int tid = threadIdx.x;
    const int l = tid & 63, wvid = tid >> 6;   // wave -> couts wvid*16 .. +15
    const int g = l >> 4, ln = l & 15;
    const int ow0 = blockIdx.x * 64;
    const int band = blockIdx.y;               // rows band*64..+63
    const int n = blockIdx.z;

    // ---- persistent weights: A[h][tap], 18 x half8 = 72 VGPR; lane ln -> cout ----
    const char* wl = (const char*)w_t + g * 2048 + (wvid * 16 + ln) * 16;
    half8_t A[2][9];
#pragma unroll
    for (int h = 0; h < 2; ++h)
#pragma unroll
        for (int tp = 0; tp < 9; ++tp)
            A[h][tp] = *(const half8_t*)(wl + h * 8192 + tp * 16384);

    // per-lane bias (cout = wvid*16 + ln), broadcast to all 4 pixel slots
    const float bv = bias[wvid * 16 + ln];

    // ---- per-lane LDS byte offsets: F[cgf][kx][h] (verified formula) ----
    int F[4][3][2];
#pragma unroll
    for (int cgf = 0; cgf < 4; ++cgf)
#pragma unroll
        for (int kx = 0; kx < 3; ++kx)
#pragma unroll
            for (int h = 0; h < 2; ++h) {
                const int c = cgf * 16 + kx + ln;
                F[cgf][kx][h] = c * 128 + (((4 * h + g) ^ (c & 7)) << 4);
            }

    const char* xbase = (const char*)xp + (size_t)n * XP_NSTRIDE * 2 + (size_t)ow0 * 128;

#define STAGE(BUFSEL, IT)                                                              \
    {                                                                                  \
        const char* gt = xbase + (size_t)(band * 64 + (IT) * 4) * XP_RSTRIDE_B;        \
        const unsigned lb = (BUFSEL) * TILE_BYTES;                                     \
        _Pragma("unroll")                                                              \
        for (int p = 0; p < 6; ++p) {                                                  \
            const int u = p * 512 + tid;                                               \
            int row = (p * 512) / 528;                                                 \
            if (u >= (row + 1) * 528) row++;                                           \
            const int rem = u - row * 528;                                             \
            const int c = rem >> 3, s = rem & 7;                                       \
            gload_lds16(gt + (size_t)row * XP_RSTRIDE_B + c * 128 +                    \
                            (((s ^ (c & 7))) << 4),                                    \
                        xs + lb + ((unsigned)(p * 512 + (tid & ~63)) << 4));           \
        }                                                                              \
        if (tid < 96) {                                                                \
            const int rem = 432 + tid;                                                 \
            const int c = rem >> 3, s = rem & 7;                                       \
            const int4 v = *(const int4*)(gt + (size_t)5 * XP_RSTRIDE_B + c * 128 +    \
                                          ((s ^ (c & 7)) << 4));                       \
            *(int4*)(xs + lb + (unsigned)(3072 + tid) * 16) = v;                       \
        }                                                                              \
    }

    STAGE(0, 0);
    asm volatile("s_waitcnt vmcnt(0) lgkmcnt(0)" ::: "memory");
    __builtin_amdgcn_s_barrier();
    __builtin_amdgcn_sched_barrier(0);

    int cur = 0;
#pragma unroll 1
    for (int it = 0; it < 16; ++it) {
        // Issue next-tile staging FIRST (oldest vmem ops -> drained by counted vmcnt).
        if (it < 15) STAGE(cur ^ 1, it + 1);

        floatx4 acc[4][4];   // [rr][cgf]; components = 4 consecutive pixels
#pragma unroll
        for (int rr = 0; rr < 4; ++rr)
#pragma unroll
            for (int cgf = 0; cgf < 4; ++cgf) acc[rr][cgf] = (floatx4){bv, bv, bv, bv};

        const unsigned char* bb = xs + cur * TILE_BYTES;
        __builtin_amdgcn_s_setprio(1);
#pragma unroll
        for (int kx = 0; kx < 3; ++kx)
#pragma unroll
            for (int h = 0; h < 2; ++h)
#pragma unroll
                for (int cgf = 0; cgf < 4; ++cgf) {
                    const unsigned char* bp = bb + F[cgf][kx][h];
                    half8_t bt[6];
#pragma unroll
                    for (int t = 0; t < 6; ++t)
                        bt[t] = *(const half8_t*)(bp + t * ROW_LDS);
#pragma unroll
                    for (int ky = 0; ky < 3; ++ky) {
                        const half8_t af = A[h][ky * 3 + kx];
#pragma unroll
                        for (int rr = 0; rr < 4; ++rr)
                            acc[rr][cgf] = __builtin_amdgcn_mfma_f32_16x16x32_f16(
                                bt[rr + ky], af, acc[rr][cgf], 0, 0, 0);  // swapped: D row=pixel
                    }
                }
        __builtin_amdgcn_s_setprio(0);

        // ---- epilogue: direct NT dwordx4 stores (lane ln = cout; r = 4 consec pixels) ----
        const int orow0 = band * 64 + it * 4;
        float* obase = out + ((size_t)(n * 128 + wvid * 16 + ln)) * 65536 +
                       (size_t)orow0 * 256 + ow0 + g * 4;
#pragma unroll
        for (int rr = 0; rr < 4; ++rr)
#pragma unroll
            for (int cgf = 0; cgf < 4; ++cgf)
                __builtin_nontemporal_store(
                    acc[rr][cgf],
                    (floatx4*)(obase + rr * 256 + cgf * 16));

        if (it < 15) {
            // Drain staging loads (oldest); leave this iter's 16 NT stores in flight.
            asm volatile("s_waitcnt vmcnt(16) lgkmcnt(0)" ::: "memory");
            __builtin_amdgcn_s_barrier();
            __builtin_amdgcn_sched_barrier(0);
        }
        cur ^= 1;
    }
#undef STAGE
}

// ---------- fallback (proven V2 fp32) if workspace too small ----------
__global__ __launch_bounds__(256) void Conv2d_fallback_kernel(
    const float* __restrict__ x, const float* __restrict__ w,
    const float* __restrict__ bias, float* __restrict__ out) {
    const int tx = threadIdx.x & 15, ty = threadIdx.x >> 4;
    const int ow0 = blockIdx.x * 64 + tx * 4;
    const int oh = blockIdx.y * 16 + ty;
    const int gg = blockIdx.z & 7, n = blockIdx.z >> 3;
    const int co = gg * 16;
    float acc[16][4];
#pragma unroll
    for (int c = 0; c < 16; ++c) {
        const float b = bias[co + c];
#pragma unroll
        for (int p = 0; p < 4; ++p) acc[c][p] = b;
    }
    const float* xn = x + (size_t)n * CIN * HH * WW;
    const float* wb = w + (size_t)co * CIN * 9;
    for (int ci = 0; ci < CIN; ++ci) {
        const float* xc = xn + (size_t)ci * HH * WW;
        float in[3][6];
#pragma unroll
        for (int ky = 0; ky < 3; ++ky) {
            const int iy = oh + ky - 1;
            if ((unsigned)iy < (unsigned)HH) {
                const float* row = xc + iy * WW;
                const float4 v = *(const float4*)(row + ow0);
                in[ky][1] = v.x; in[ky][2] = v.y; in[ky][3] = v.z; in[ky][4] = v.w;
                in[ky][0] = (ow0 > 0) ? row[ow0 - 1] : 0.0f;
                in[ky][5] = (ow0 < WW - 4) ? row[ow0 + 4] : 0.0f;
            } else {
#pragma unroll
                for (int j = 0; j < 6; ++j) in[ky][j] = 0.0f;
            }
        }
        const float* wc2 = wb + ci * 9;
#pragma unroll
        for (int c = 0; c < 16; ++c) {
            const float* wcc = wc2 + (size_t)c * CIN * 9;
#pragma unroll
            for (int ky = 0; ky < 3; ++ky)
#pragma unroll
                for (int kx = 0; kx < 3; ++kx) {
                    const float wv2 = wcc[ky * 3 + kx];
#pragma unroll
                    for (int p = 0; p < 4; ++p) acc[c][p] += in[ky][kx + p] * wv2;
                }
        }
    }
    const size_t hw = (size_t)HH * WW;
    float* ob = out + ((size_t)n * COUT + co) * hw + (size_t)oh * WW + ow0;
#pragma unroll
    for (int c = 0; c < 16; ++c) {
        float4 v;
        v.x = acc[c][0]; v.y = acc[c][1]; v.z = acc[c][2]; v.w = acc[c][3];
        *(float4*)(ob + (size_t)c * hw) = v;
    }
}

extern "C" void kernel_launch(void* const* d_in, const int* in_sizes, int n_in,
                              void* d_out, int out_size, void* d_ws, size_t ws_size,
                              hipStream_t stream) {
    const float* x = (const float*)d_in[0];
    const float* w = (const float*)d_in[1];
    const float* b = (const float*)d_in[2];
    float* out = (float*)d_out;

    const size_t xp_bytes = (size_t)NB * XP_NSTRIDE * 2;      // 136.3 MB
    const size_t wt_bytes = (size_t)9 * 8 * 128 * 8 * 2;      // 144 KiB

    if (ws_size >= xp_bytes + wt_bytes) {
        char* ws = (char*)d_ws;
        _Float16* xp = (_Float16*)ws;
        _Float16* w_t = (_Float16*)(ws + xp_bytes);
        Conv2d_wprep_kernel<<<dim3(288), 256, 0, stream>>>(w, w_t);
        Conv2d_xpad_zero_kernel<<<dim3(33, 16), 256, 0, stream>>>(xp);
        Conv2d_xprep_kernel<<<dim3(2, 256, 16), 256, 0, stream>>>(x, xp);
        Conv2dManual_77695958385099_kernel<<<dim3(4, 4, 16), 512, 0, stream>>>(
            xp, w_t, b, out);
    } else {
        dim3 grid(WW / 64, HH / 16, NB * (COUT / 16));
        Conv2d_fallback_kernel<<<grid, 256, 0, stream>>>(x, w, b, out);
    }
}

// Round 8
// 763.198 us; speedup vs baseline: 1.1117x; 1.1117x over previous
//
#include <hip/hip_runtime.h>

// Conv2d 3x3 SAME, stride 1: x (16,64,256,256) f32, w (128,64,3,3), bias (128) -> out (16,128,256,256)
//
// V9: fp16 MFMA implicit-GEMM = V7 skeleton + V8's swapped-operand acc + b128 scratch epilogue.
//  - x -> padded NHWC f16 workspace x_p[n][258][258][64] (1-px zero border).
//  - conv: 256 blocks (4 strips x 4 bands x 16 n) x 512 thr; 8 waves x 16 couts each.
//    Per-wave A = 18 half8 = 72 VGPR, register-persistent.
//  - Swapped mfma(bt, af, acc): D row=pixel, col=cout (HW-verified in V8) -> each acc frag
//    is 4 CONSECUTIVE pixels -> scratch transpose writes are 16x ds_write_b128 (was 64x b32).
//  - Epilogue: per-wave LDS scratch (stride 68 floats; write banks 4*((ln+g)%8), disjoint
//    4-bank spans -> conflict-free) -> NT dwordx4 stores, 16 lanes = 256B contiguous =
//    full 128B lines per instruction (V8's direct stores were 64B/plane scatter -> ~2x
//    write amplification, the -72us regression).
//  - No setprio (T5 is null-to-negative on lockstep GEMM structures, m190).
//  - Raw s_barrier + counted s_waitcnt vmcnt(16): staging drains, 16 NT stores/iter stay
//    in flight across the barrier. Staging/swizzle bit-identical to verified V4..V8.

typedef _Float16 half8_t __attribute__((ext_vector_type(8)));
typedef float floatx4 __attribute__((ext_vector_type(4)));

#define HH 256
#define WW 256
#define CIN 64
#define COUT 128
#define NB 16

#define XP_RSTRIDE   16512            // halves per padded row (258*64)
#define XP_NSTRIDE   4260096          // halves per n (258*16512)
#define XP_RSTRIDE_B 33024            // bytes per padded row
#define ROW_LDS      8448             // bytes per LDS tile row (66 cols * 128 B)
#define TILE_BYTES   50688            // 6 * ROW_LDS

__device__ inline void gload_lds16(const void* g, void* l) {
    __builtin_amdgcn_global_load_lds(
        (const __attribute__((address_space(1))) unsigned int*)g,
        (__attribute__((address_space(3))) unsigned int*)l, 16, 0, 0);
}

// ---------- pass 1a: weights OIHW f32 -> w_t[9][8][128][8] f16 ----------
__global__ void Conv2d_wprep_kernel(const float* __restrict__ w, _Float16* __restrict__ w_t) {
    int idx = blockIdx.x * 256 + threadIdx.x;
    if (idx >= 9 * 8 * 128 * 8) return;
    const int j = idx & 7, cout = (idx >> 3) & 127, s = (idx >> 10) & 7, t = idx >> 13;
    w_t[idx] = (_Float16)w[(cout * 64 + s * 8 + j) * 9 + t];
}

// ---------- pass 1b-zero: zero the 1-px border of x_p ----------
__global__ void Conv2d_xpad_zero_kernel(_Float16* __restrict__ xp) {
    const int idx = blockIdx.x * 256 + threadIdx.x;   // 16B units, 8224 per n
    const int n = blockIdx.y;
    if (idx >= 8224) return;
    size_t off;  // in halves
    if (idx < 2064)      off = (size_t)idx * 8;                                    // row 0
    else if (idx < 4128) off = (size_t)257 * XP_RSTRIDE + (size_t)(idx - 2064) * 8; // row 257
    else if (idx < 6176) { const int t = idx - 4128;                               // col 0
        off = (size_t)(1 + (t >> 3)) * XP_RSTRIDE + (size_t)(t & 7) * 8; }
    else { const int t = idx - 6176;                                               // col 257
        off = (size_t)(1 + (t >> 3)) * XP_RSTRIDE + 257 * 64 + (size_t)(t & 7) * 8; }
    int4 z = {0, 0, 0, 0};
    *(int4*)(xp + (size_t)n * XP_NSTRIDE + off) = z;
}

// ---------- pass 1b: x NCHW f32 -> padded NHWC f16 (LDS-free transpose) ----------
__global__ __launch_bounds__(256) void Conv2d_xprep_kernel(const float* __restrict__ x,
                                                           _Float16* __restrict__ xp) {
    const int tid = threadIdx.x;
    const int u = tid & 7, colq = tid >> 3;
    const int n = blockIdx.z, h = blockIdx.y;
    const int col0 = blockIdx.x * 128 + colq * 4;

    float4 in[8];
#pragma unroll
    for (int j = 0; j < 8; ++j)
        in[j] = *(const float4*)(x + ((size_t)((n * 64 + u * 8 + j) * 256 + h) * 256) + col0);

    _Float16* dst = xp + (size_t)n * XP_NSTRIDE + (size_t)(h + 1) * XP_RSTRIDE +
                    (size_t)(col0 + 1) * 64 + u * 8;
#pragma unroll
    for (int i = 0; i < 4; ++i) {
        half8_t hv;
#pragma unroll
        for (int j = 0; j < 8; ++j) hv[j] = (_Float16)((const float*)&in[j])[i];
        *(half8_t*)(dst + (size_t)i * 64) = hv;
    }
}

// ---------- conv: persistent strips, register weights, b128-scratch epilogue ----------
__global__ __launch_bounds__(512, 2) void Conv2dManual_77695958385099_kernel(
    const _Float16* __restrict__ xp, const _Float16* __restrict__ w_t,
    const float* __restrict__ bias, float* __restrict__ out) {
    __shared__ __align__(16) unsigned char xs[2 * TILE_BYTES];  // 101376 B
    __shared__ __align__(16) float esc[8][1088];                // 34816 B
    const int tid = threadIdx.x;
    const int l = tid & 63, wvid = tid >> 6;   // wave -> couts wvid*16 .. +15
    const int g = l >> 4, ln = l & 15;
    const int ow0 = blockIdx.x * 64;
    const int band = blockIdx.y;               // rows band*64..+63
    const int n = blockIdx.z;

    // ---- persistent weights: A[h][tap], 18 x half8 = 72 VGPR; lane ln -> cout ----
    const char* wl = (const char*)w_t + g * 2048 + (wvid * 16 + ln) * 16;
    half8_t A[2][9];
#pragma unroll
    for (int h = 0; h < 2; ++h)
#pragma unroll
        for (int tp = 0; tp < 9; ++tp)
            A[h][tp] = *(const half8_t*)(wl + h * 8192 + tp * 16384);

    // per-lane bias (cout = wvid*16 + ln), broadcast to all 4 pixel slots
    const float bv = bias[wvid * 16 + ln];

    // ---- per-lane LDS byte offsets: F[cgf][kx][h] (verified formula) ----
    int F[4][3][2];
#pragma unroll
    for (int cgf = 0; cgf < 4; ++cgf)
#pragma unroll
        for (int kx = 0; kx < 3; ++kx)
#pragma unroll
            for (int h = 0; h < 2; ++h) {
                const int c = cgf * 16 + kx + ln;
                F[cgf][kx][h] = c * 128 + (((4 * h + g) ^ (c & 7)) << 4);
            }

    const char* xbase = (const char*)xp + (size_t)n * XP_NSTRIDE * 2 + (size_t)ow0 * 128;

#define STAGE(BUFSEL, IT)                                                              \
    {                                                                                  \
        const char* gt = xbase + (size_t)(band * 64 + (IT) * 4) * XP_RSTRIDE_B;        \
        const unsigned lb = (BUFSEL) * TILE_BYTES;                                     \
        _Pragma("unroll")                                                              \
        for (int p = 0; p < 6; ++p) {                                                  \
            const int u = p * 512 + tid;                                               \
            int row = (p * 512) / 528;                                                 \
            if (u >= (row + 1) * 528) row++;                                           \
            const int rem = u - row * 528;                                             \
            const int c = rem >> 3, s = rem & 7;                                       \
            gload_lds16(gt + (size_t)row * XP_RSTRIDE_B + c * 128 +                    \
                            (((s ^ (c & 7))) << 4),                                    \
                        xs + lb + ((unsigned)(p * 512 + (tid & ~63)) << 4));           \
        }                                                                              \
        if (tid < 96) {                                                                \
            const int rem = 432 + tid;                                                 \
            const int c = rem >> 3, s = rem & 7;                                       \
            const int4 v = *(const int4*)(gt + (size_t)5 * XP_RSTRIDE_B + c * 128 +    \
                                          ((s ^ (c & 7)) << 4));                       \
            *(int4*)(xs + lb + (unsigned)(3072 + tid) * 16) = v;                       \
        }                                                                              \
    }

    STAGE(0, 0);
    asm volatile("s_waitcnt vmcnt(0) lgkmcnt(0)" ::: "memory");
    __builtin_amdgcn_s_barrier();
    __builtin_amdgcn_sched_barrier(0);

    int cur = 0;
#pragma unroll 1
    for (int it = 0; it < 16; ++it) {
        // Issue next-tile staging FIRST (oldest vmem ops -> drained by counted vmcnt).
        if (it < 15) STAGE(cur ^ 1, it + 1);

        floatx4 acc[4][4];   // [rr][cgf]; components = 4 consecutive pixels
#pragma unroll
        for (int rr = 0; rr < 4; ++rr)
#pragma unroll
            for (int cgf = 0; cgf < 4; ++cgf) acc[rr][cgf] = (floatx4){bv, bv, bv, bv};

        const unsigned char* bb = xs + cur * TILE_BYTES;
#pragma unroll
        for (int kx = 0; kx < 3; ++kx)
#pragma unroll
            for (int h = 0; h < 2; ++h)
#pragma unroll
                for (int cgf = 0; cgf < 4; ++cgf) {
                    const unsigned char* bp = bb + F[cgf][kx][h];
                    half8_t bt[6];
#pragma unroll
                    for (int t = 0; t < 6; ++t)
                        bt[t] = *(const half8_t*)(bp + t * ROW_LDS);
#pragma unroll
                    for (int ky = 0; ky < 3; ++ky) {
                        const half8_t af = A[h][ky * 3 + kx];
#pragma unroll
                        for (int rr = 0; rr < 4; ++rr)
                            acc[rr][cgf] = __builtin_amdgcn_mfma_f32_16x16x32_f16(
                                bt[rr + ky], af, acc[rr][cgf], 0, 0, 0);  // D row=pixel
                    }
                }

        // ---- epilogue: b128 scratch transpose -> full-line NT dwordx4 stores ----
        float* scr = &esc[wvid][0];
        const int orow0 = band * 64 + it * 4;
        float* obase = out + ((size_t)(n * 128 + wvid * 16)) * 65536 +
                       (size_t)orow0 * 256 + ow0;
#pragma unroll
        for (int rr = 0; rr < 4; ++rr) {
            // write: cout=ln row of 64 px; px = cgf*16 + g*4 + comp
#pragma unroll
            for (int cgf = 0; cgf < 4; ++cgf)
                *(floatx4*)(scr + ln * 68 + cgf * 16 + g * 4) = acc[rr][cgf];
            // read+store: co = q*4+g plane, 16 lanes x 16B = 256B contiguous
#pragma unroll
            for (int q = 0; q < 4; ++q) {
                const int co = q * 4 + g;
                const floatx4 v = *(const floatx4*)(scr + co * 68 + ln * 4);
                __builtin_nontemporal_store(
                    v, (floatx4*)(obase + (size_t)co * 65536 + rr * 256 + ln * 4));
            }
        }

        if (it < 15) {
            // Drain staging loads (oldest); leave this iter's 16 NT stores in flight.
            asm volatile("s_waitcnt vmcnt(16) lgkmcnt(0)" ::: "memory");
            __builtin_amdgcn_s_barrier();
            __builtin_amdgcn_sched_barrier(0);
        }
        cur ^= 1;
    }
#undef STAGE
}

// ---------- fallback (proven V2 fp32) if workspace too small ----------
__global__ __launch_bounds__(256) void Conv2d_fallback_kernel(
    const float* __restrict__ x, const float* __restrict__ w,
    const float* __restrict__ bias, float* __restrict__ out) {
    const int tx = threadIdx.x & 15, ty = threadIdx.x >> 4;
    const int ow0 = blockIdx.x * 64 + tx * 4;
    const int oh = blockIdx.y * 16 + ty;
    const int gg = blockIdx.z & 7, n = blockIdx.z >> 3;
    const int co = gg * 16;
    float acc[16][4];
#pragma unroll
    for (int c = 0; c < 16; ++c) {
        const float b = bias[co + c];
#pragma unroll
        for (int p = 0; p < 4; ++p) acc[c][p] = b;
    }
    const float* xn = x + (size_t)n * CIN * HH * WW;
    const float* wb = w + (size_t)co * CIN * 9;
    for (int ci = 0; ci < CIN; ++ci) {
        const float* xc = xn + (size_t)ci * HH * WW;
        float in[3][6];
#pragma unroll
        for (int ky = 0; ky < 3; ++ky) {
            const int iy = oh + ky - 1;
            if ((unsigned)iy < (unsigned)HH) {
                const float* row = xc + iy * WW;
                const float4 v = *(const float4*)(row + ow0);
                in[ky][1] = v.x; in[ky][2] = v.y; in[ky][3] = v.z; in[ky][4] = v.w;
                in[ky][0] = (ow0 > 0) ? row[ow0 - 1] : 0.0f;
                in[ky][5] = (ow0 < WW - 4) ? row[ow0 + 4] : 0.0f;
            } else {
#pragma unroll
                for (int j = 0; j < 6; ++j) in[ky][j] = 0.0f;
            }
        }
        const float* wc2 = wb + ci * 9;
#pragma unroll
        for (int c = 0; c < 16; ++c) {
            const float* wcc = wc2 + (size_t)c * CIN * 9;
#pragma unroll
            for (int ky = 0; ky < 3; ++ky)
#pragma unroll
                for (int kx = 0; kx < 3; ++kx) {
                    const float wv2 = wcc[ky * 3 + kx];
#pragma unroll
                    for (int p = 0; p < 4; ++p) acc[c][p] += in[ky][kx + p] * wv2;
                }
        }
    }
    const size_t hw = (size_t)HH * WW;
    float* ob = out + ((size_t)n * COUT + co) * hw + (size_t)oh * WW + ow0;
#pragma unroll
    for (int c = 0; c < 16; ++c) {
        float4 v;
        v.x = acc[c][0]; v.y = acc[c][1]; v.z = acc[c][2]; v.w = acc[c][3];
        *(float4*)(ob + (size_t)c * hw) = v;
    }
}

extern "C" void kernel_launch(void* const* d_in, const int* in_sizes, int n_in,
                              void* d_out, int out_size, void* d_ws, size_t ws_size,
                              hipStream_t stream) {
    const float* x = (const float*)d_in[0];
    const float* w = (const float*)d_in[1];
    const float* b = (const float*)d_in[2];
    float* out = (float*)d_out;

    const size_t xp_bytes = (size_t)NB * XP_NSTRIDE * 2;      // 136.3 MB
    const size_t wt_bytes = (size_t)9 * 8 * 128 * 8 * 2;      // 144 KiB

    if (ws_size >= xp_bytes + wt_bytes) {
        char* ws = (char*)d_ws;
        _Float16* xp = (_Float16*)ws;
        _Float16* w_t = (_Float16*)(ws + xp_bytes);
        Conv2d_wprep_kernel<<<dim3(288), 256, 0, stream>>>(w, w_t);
        Conv2d_xpad_zero_kernel<<<dim3(33, 16), 256, 0, stream>>>(xp);
        Conv2d_xprep_kernel<<<dim3(2, 256, 16), 256, 0, stream>>>(x, xp);
        Conv2dManual_77695958385099_kernel<<<dim3(4, 4, 16), 512, 0, stream>>>(
            xp, w_t, b, out);
    } else {
        dim3 grid(WW / 64, HH / 16, NB * (COUT / 16));
        Conv2d_fallback_kernel<<<grid, 256, 0, stream>>>(x, w, b, out);
    }
}